// Round 6
// baseline (89.659 us; speedup 1.0000x reference)
//
#include <hip/hip_runtime.h>

#define C 161
#define C3 4173281            // 161^3 cells
#define NVERT_ELEMS 12519843  // C3*3
#define APQ 4121600           // 161*160*160 quads per axis
#define TQ 12364800           // 3*APQ
#define TOTQ_ELEMS 49459200   // 4*TQ
#define NQB 48300             // TQ/256
#define NVBLK 13041           // 161 * 81  (cx × cy-pair)

// round f32 to nearest bf16 (RNE), return as f32
__device__ __forceinline__ float bf16r(float f) {
    union { float f; unsigned int u; } v; v.f = f;
    v.u += 0x7FFFu + ((v.u >> 16) & 1u);
    v.u &= 0xFFFF0000u;
    return v.f;
}

// Block = cells (cx, cy0..cy0+1, 0..160). Stage the 6 padded point-rows
// (px in {cx,cx+1} x py in {cy0..cy0+2}, pz in [0,162)) into LDS once;
// compute cells entirely from LDS with no bounds logic.
__global__ __launch_bounds__(256) void verts_kernel(const float* __restrict__ grid,
                                                    const float* __restrict__ deform,
                                                    float* __restrict__ out) {
    __shared__ float sg[972], sdx[972], sdy[972], sdz[972];
    __shared__ float sv[966];
    int b = blockIdx.x, t = threadIdx.x;
    int cx = b / 81;
    int cy0 = (b - cx * 81) * 2;
    int NC = (cy0 == 160) ? 161 : 322;   // cells in this block

    // ---- stage 972 padded points: row = (px-cx)*3 + (py-cy0), z = pz ----
    for (int p = t; p < 972; p += 256) {
        int row = p / 162;
        int pz = p - row * 162;
        int hx = (row >= 3) ? 1 : 0;
        int px = cx + hx;
        int py = cy0 + row - 3 * hx;
        int gx = px - 1, gy = py - 1, gz = pz - 1;
        bool in = ((unsigned)gx < 160u) & ((unsigned)gy < 160u) & ((unsigned)gz < 160u);
        int ix = min(max(gx, 0), 159);
        int iy = min(max(gy, 0), 159);
        int iz = min(max(gz, 0), 159);
        int idx = (ix * 160 + iy) * 160 + iz;
        float gvv = grid[idx];
        const float* dp = deform + (size_t)idx * 3;
        float d0 = dp[0], d1 = dp[1], d2 = dp[2];
        sg[p]  = in ? gvv : 1.0f;
        sdx[p] = in ? d0 : 0.f;
        sdy[p] = in ? d1 : 0.f;
        sdz[p] = in ? d2 : 0.f;
    }
    __syncthreads();

    // ---- compute cells from LDS ----
    for (int lc = t; lc < NC; lc += 256) {
        int lr = (lc >= 161) ? 1 : 0;
        int lz = lc - 161 * lr;
        float gv[8], px_[8], py_[8], pz_[8];
#pragma unroll
        for (int c = 0; c < 8; ++c) {
            int dx = (c >> 2) & 1, dy = (c >> 1) & 1, dz = c & 1;
            int idx = (dx * 3 + lr + dy) * 162 + lz + dz;
            gv[c]  = sg[idx];
            px_[c] = (float)(cx + dx)       + sdx[idx];
            py_[c] = (float)(cy0 + lr + dy) + sdy[idx];
            pz_[c] = (float)(lz + dz)       + sdz[idx];
        }

        float vs0 = 0.f, vs1 = 0.f, vs2 = 0.f, cnt = 0.f;
#pragma unroll
        for (int a = 0; a < 3; ++a) {
            int step = (a == 0) ? 4 : ((a == 1) ? 2 : 1);
#pragma unroll
            for (int c = 0; c < 8; ++c) {
                if (c & step) continue;
                int c1 = c | step;
                float g0 = gv[c], g1 = gv[c1];
                if ((g0 < 0.f) != (g1 < 0.f)) {
                    float tt = g0 * __builtin_amdgcn_rcpf(g0 - g1);
                    vs0 += px_[c] + tt * (px_[c1] - px_[c]);
                    vs1 += py_[c] + tt * (py_[c1] - py_[c]);
                    vs2 += pz_[c] + tt * (pz_[c1] - pz_[c]);
                    cnt += 1.f;
                }
            }
        }

        float v0, v1, v2;
        if (cnt > 0.f) {
            float inv = __builtin_amdgcn_rcpf(cnt);
            v0 = vs0 * inv; v1 = vs1 * inv; v2 = vs2 * inv;
        } else {
            v0 = v1 = v2 = 0.f;
        }
        const float s = 1.0f / 159.0f;
        sv[lc * 3 + 0] = bf16r((v0 - 1.f) * s);
        sv[lc * 3 + 1] = bf16r((v1 - 1.f) * s);
        sv[lc * 3 + 2] = bf16r((v2 - 1.f) * s);
    }
    __syncthreads();

    // ---- aligned coalesced store of N consecutive floats at out[G..G+N) ----
    int S0 = (cx * 161 + cy0) * 161;
    int N = NC * 3;
    int G = S0 * 3;
    int A = (4 - (G & 3)) & 3;          // scalar head to reach 16B alignment
    if (t < A) out[G + t] = sv[t];
    int main_end = A + ((N - A) & ~3);
    for (int j = A + (t << 2); j < main_end; j += 1024) {
        float4 v;
        v.x = sv[j]; v.y = sv[j + 1]; v.z = sv[j + 2]; v.w = sv[j + 3];
        *(float4*)(out + G + j) = v;
    }
    int k = main_end + t;
    if (k < N) out[G + k] = sv[k];
}

// quad values (elements 0..3, bf16-rounded floats) for quad q; axis-specialized loads
__device__ __forceinline__ float4 quad_vals(const float* __restrict__ grid, int q) {
    int a = q / APQ;
    int rem = q - a * APQ;
    int q0, q1, q2, q3;
    float g0, g1;
    if (a == 0) {
        int i2 = rem % 160; int r = rem / 160; int i1 = r % 160; int i0 = r / 160;
        int ex = i0, ey = i1 + 1, ez = i2 + 1;          // ex in [0,160]
        int pb = i1 * 160 + i2;
        int a0 = max(ex - 1, 0), a1 = min(ex, 159);
        float g0r = grid[a0 * 25600 + pb], g1r = grid[a1 * 25600 + pb];
        g0 = (ex >= 1)   ? g0r : 1.0f;
        g1 = (ex <= 159) ? g1r : 1.0f;
        int b = (ex * C + ey) * C + ez;
        q0 = b - C - 1; q1 = b - 1; q2 = b; q3 = b - C;
    } else if (a == 1) {
        int i2 = rem % 160; int r = rem / 160; int i1 = r % 161; int i0 = r / 161;
        int ex = i0 + 1, ey = i1, ez = i2 + 1;          // ey in [0,160]
        int pb = (ex - 1) * 25600 + i2;
        int a0 = max(ey - 1, 0), a1 = min(ey, 159);
        float g0r = grid[pb + a0 * 160], g1r = grid[pb + a1 * 160];
        g0 = (ey >= 1)   ? g0r : 1.0f;
        g1 = (ey <= 159) ? g1r : 1.0f;
        int b = (ex * C + ey) * C + ez;
        q0 = b - C * C - 1; q1 = b - 1; q2 = b; q3 = b - C * C;
    } else {
        int i2 = rem % 161; int r = rem / 161; int i1 = r % 160; int i0 = r / 160;
        int ex = i0 + 1, ey = i1 + 1, ez = i2;          // ez in [0,160]
        int pb = ((ex - 1) * 160 + i1) * 160;
        int a0 = max(ez - 1, 0), a1 = min(ez, 159);
        float g0r = grid[pb + a0], g1r = grid[pb + a1];
        g0 = (ez >= 1)   ? g0r : 1.0f;
        g1 = (ez <= 159) ? g1r : 1.0f;
        int b = (ex * C + ey) * C + ez;
        q0 = b - C * C - C; q1 = b - C; q2 = b; q3 = b - C * C;
    }
    float4 w;
    bool m = (g0 < 0.f) != (g1 < 0.f);
    if (!m) {
        w.x = w.y = w.z = w.w = -1.0f;
    } else {
        int a0, a1, a2, a3;
        if (g0 < 0.f) { a0 = q0; a1 = q1; a2 = q2; a3 = q3; }
        else          { a0 = q3; a1 = q2; a2 = q1; a3 = q0; }
        w.x = bf16r((float)a0);
        w.y = bf16r((float)a1);
        w.z = bf16r((float)a2);
        w.w = bf16r((float)a3);
    }
    return w;
}

__global__ __launch_bounds__(256) void quads_kernel(const float* __restrict__ grid,
                                                    float* __restrict__ out) {
    __shared__ __align__(16) float sq[1024];
    int b = blockIdx.x, t = threadIdx.x;
    int q = (b << 8) + t;
    float4 w = quad_vals(grid, q);
    // shifted window: sq[i] holds global element NVERT + 1 + 1024*b + i
    sq[(t << 2) + 0] = w.y;
    sq[(t << 2) + 1] = w.z;
    sq[(t << 2) + 2] = w.w;
    if (t > 0) sq[(t << 2) - 1] = w.x;
    if (t == 255) {
        int q2 = q + 1;
        if (q2 < TQ) {
            float4 w2 = quad_vals(grid, q2);
            sq[1023] = w2.x;
        }
    }
    if (b == 0 && t == 0) out[NVERT_ELEMS] = w.x;  // head element

    __syncthreads();
    int avail = TOTQ_ELEMS - 1 - (b << 10);
    if (avail > 1024) avail = 1024;
    int off = t << 2;
    float* gp = out + NVERT_ELEMS + 1 + ((size_t)b << 10);
    if (off + 4 <= avail) {
        float4 v = *(const float4*)&sq[off];
        *(float4*)(gp + off) = v;
    } else if (off < avail) {
        for (int k = off; k < avail; ++k) gp[k] = sq[k];
    }
}

extern "C" void kernel_launch(void* const* d_in, const int* in_sizes, int n_in,
                              void* d_out, int out_size, void* d_ws, size_t ws_size,
                              hipStream_t stream) {
    const float* grid   = (const float*)d_in[0];
    const float* deform = (const float*)d_in[1];
    float* out = (float*)d_out;

    hipLaunchKernelGGL(verts_kernel, dim3(NVBLK), dim3(256), 0, stream, grid, deform, out);
    hipLaunchKernelGGL(quads_kernel, dim3(NQB), dim3(256), 0, stream, grid, out);
}